// Round 10
// baseline (2814.676 us; speedup 1.0000x reference)
//
#include <hip/hip_runtime.h>

typedef _Float16 half8  __attribute__((ext_vector_type(8)));
typedef _Float16 half4v __attribute__((ext_vector_type(4)));
typedef float    floatx4 __attribute__((ext_vector_type(4)));
typedef unsigned long long u64;

#define B_ 32
#define S_ 512
#define I_ 1024
#define H_ 1024
#define M_TOT (B_ * S_)   // 16384

// ---------------------------------------------------------------------------
// fp32 -> fp16 conversion (vectorized, grid-stride), n multiple of 4
// ---------------------------------------------------------------------------
__global__ void cvt_f32_f16(const float* __restrict__ src, _Float16* __restrict__ dst, long n) {
  long i = ((long)blockIdx.x * blockDim.x + threadIdx.x) * 4;
  const long stride = (long)gridDim.x * blockDim.x * 4;
  for (; i < n; i += stride) {
    floatx4 v = *(const floatx4*)(src + i);
    half4v h = {(_Float16)v[0], (_Float16)v[1], (_Float16)v[2], (_Float16)v[3]};
    *(half4v*)(dst + i) = h;
  }
}

__global__ void bias_sum_kernel(const float* __restrict__ bihf, const float* __restrict__ bhhf,
                                const float* __restrict__ bihb, const float* __restrict__ bhhb,
                                float* __restrict__ bias, unsigned int* __restrict__ ctrs) {
  int i = blockIdx.x * blockDim.x + threadIdx.x;
  if (i < 1024) {  // zero the counter region each launch (replay-safe)
    __hip_atomic_store(ctrs + i, 0u, __ATOMIC_RELAXED, __HIP_MEMORY_SCOPE_AGENT);
  }
  if (i < H_) {
    bias[i]      = bihf[i] + bhhf[i];
    bias[H_ + i] = bihb[i] + bhhb[i];
  }
}

// ---------------------------------------------------------------------------
// GEMM: xp[dir][m][n] = sum_k x16[m][k] * W16[dir][n][k] + bias[dir][n]
// stored into out[m*2048 + dir*1024 + n] (xp lives in d_out; scan updates it
// in place).
// ---------------------------------------------------------------------------
__global__ void __launch_bounds__(256) gemm_xp_kernel(
    const _Float16* __restrict__ A,
    const _Float16* __restrict__ W,
    const float*    __restrict__ bias,
    float*          __restrict__ out)
{
  __shared__ _Float16 alds[128 * 32];
  __shared__ _Float16 blds[128 * 32];

  const int dir = blockIdx.z;
  const int m0  = blockIdx.y * 128;
  const int n0  = blockIdx.x * 128;
  const int tid  = threadIdx.x;
  const int lane = tid & 63;
  const int wv   = tid >> 6;
  const int wm   = wv >> 1, wn = wv & 1;
  const int lrow = lane & 15;
  const int lkg  = lane >> 4;

  const _Float16* Wd = W + (long)dir * H_ * I_;

  floatx4 acc[4][4] = {};

  const int srow = tid >> 1;
  const int sseg = tid & 1;

  for (int kt = 0; kt < 32; ++kt) {
    __syncthreads();
    {
      const _Float16* srcA = A  + (long)(m0 + srow) * I_ + kt * 32 + sseg * 16;
      const _Float16* srcB = Wd + (long)(n0 + srow) * I_ + kt * 32 + sseg * 16;
      half8 a0 = *(const half8*)(srcA);
      half8 a1 = *(const half8*)(srcA + 8);
      half8 b0 = *(const half8*)(srcB);
      half8 b1 = *(const half8*)(srcB + 8);
      const int sw = (srow & 7) << 4;
      const int base = srow * 64 + sseg * 32;
      *(half8*)((char*)alds + ((base     ) ^ sw)) = a0;
      *(half8*)((char*)alds + ((base + 16) ^ sw)) = a1;
      *(half8*)((char*)blds + ((base     ) ^ sw)) = b0;
      *(half8*)((char*)blds + ((base + 16) ^ sw)) = b1;
    }
    __syncthreads();

    half8 af[4], bf[4];
#pragma unroll
    for (int mt = 0; mt < 4; ++mt) {
      int r = wm * 64 + mt * 16 + lrow;
      int byte = (r * 64 + lkg * 16) ^ ((r & 7) << 4);
      af[mt] = *(const half8*)((const char*)alds + byte);
    }
#pragma unroll
    for (int ntt = 0; ntt < 4; ++ntt) {
      int r = wn * 64 + ntt * 16 + lrow;
      int byte = (r * 64 + lkg * 16) ^ ((r & 7) << 4);
      bf[ntt] = *(const half8*)((const char*)blds + byte);
    }
#pragma unroll
    for (int mt = 0; mt < 4; ++mt)
#pragma unroll
      for (int ntt = 0; ntt < 4; ++ntt)
        acc[mt][ntt] = __builtin_amdgcn_mfma_f32_16x16x32_f16(af[mt], bf[ntt], acc[mt][ntt], 0, 0, 0);
  }

#pragma unroll
  for (int mt = 0; mt < 4; ++mt) {
    int mrow = m0 + wm * 64 + mt * 16 + lkg * 4;
#pragma unroll
    for (int ntt = 0; ntt < 4; ++ntt) {
      int n = n0 + wn * 64 + ntt * 16 + lrow;
      float bv = bias[dir * H_ + n];
#pragma unroll
      for (int v = 0; v < 4; ++v) {
        out[(long)(mrow + v) * (2 * H_) + dir * H_ + n] = acc[mt][ntt][v] + bv;
      }
    }
  }
}

// ---------------------------------------------------------------------------
// Recurrent scan, 64-row-block edition (halved sc1 traffic).
// 32 WGs: dir = wg>>4, rb = wg&15 owns rows [rb*64, rb*64+64) of its dir.
// W_hh block = 64x1024 f16 = 128 KiB LDS (+16 KiB reduce = 144 KiB).
// Waves = (nt batch-half, kh K-half). Each wave: 4 row-tiles x 16 kt
// = 64 MFMAs/step; h-read = 16 batches x its K-half once -> per-dir h (64KB)
// read once per WG: 2 MB/step grid-wide (was 4 MB in R9).
// Sync (proven R9 pattern, re-keyed): 16 monotonic sub-counters, 128 B apart,
// line = ((dir*2+nt)*2+kh)*2 + (rb>>3), 8 waves deep. Signal: each wave after
// its own h-store vmcnt(0) ack. Poll: 4 lines of own (dir,nt), lanes 0..3,
// target 8*(t+1). Overwrite-safety: poll >= 8(t+1) <=> all (dir,nt) waves
// finished reading h[t-1] => safe to write h[t+1] over it (same induction as
// R9). One unconditional __syncthreads/step (parity-buffered redlds).
// ---------------------------------------------------------------------------
__global__ void __launch_bounds__(256, 1) scan_kernel(
    const float* __restrict__ Whh_f,
    const float* __restrict__ Whh_b,
    float*       __restrict__ out,     // [B][S][2H]; holds xp on entry
    _Float16*    __restrict__ hbuf,    // [2 buf][2 dir][B][H] f16
    unsigned int* __restrict__ ctrs)   // 16 sub-counters, 128 B apart
{
  __shared__ _Float16 wlds[64 * 1024];       // 128 KiB
  __shared__ floatx4  redlds[2 * 4 * 2 * 64]; // 16 KiB [parity][rt][nt][lane]

  const int w     = blockIdx.x;    // 0..31
  const int dir   = w >> 4;
  const int rb    = w & 15;
  const int rows0 = rb * 64;
  const float* Whh = dir ? Whh_b : Whh_f;
  const int tid = threadIdx.x;

  // stage W_hh rows [rows0, rows0+64) as f16, swizzled: byte ^= (row&7)<<4
  for (int idx = tid; idx < 64 * 128; idx += 256) {
    const int r  = idx >> 7;    // 0..63
    const int kg = idx & 127;
    const float* src = Whh + (long)(rows0 + r) * H_ + kg * 8;
    floatx4 v0 = *(const floatx4*)(src);
    floatx4 v1 = *(const floatx4*)(src + 4);
    half8 h = {(_Float16)v0[0], (_Float16)v0[1], (_Float16)v0[2], (_Float16)v0[3],
               (_Float16)v1[0], (_Float16)v1[1], (_Float16)v1[2], (_Float16)v1[3]};
    const int byte = (r * 2048 + kg * 16) ^ ((r & 7) << 4);
    *(half8*)((char*)wlds + byte) = h;
  }

  // wave/lane roles
  const int lane = tid & 63;
  const int wv   = tid >> 6;
  const int nt   = wv & 1;          // batch half
  const int kh   = wv >> 1;         // K half; owns row-tiles {kh*2, kh*2+1}
  const int lrow = lane & 15;
  const int lkg  = lane >> 4;       // 0..3
  const int b_idx = nt * 16 + lrow; // batch
  const int kbase = kh * 512;       // K-half start (halves)
  const int asw   = (lrow & 7) << 4;
  // row byte bases for the 4 row-tiles (rows rt*16+lrow)
  const int abase0 = (lrow     ) * 2048 + kbase * 2;
  const int abase1 = (lrow + 16) * 2048 + kbase * 2;
  const int abase2 = (lrow + 32) * 2048 + kbase * 2;
  const int abase3 = (lrow + 48) * 2048 + kbase * 2;
  // owned output rows (two 4-row groups)
  const int r0a = rows0 + (kh * 2    ) * 16 + lkg * 4;
  const int r0b = rows0 + (kh * 2 + 1) * 16 + lkg * 4;

  unsigned int* sig  = ctrs + ((((dir * 2 + nt) * 2 + kh) * 2) + (rb >> 3)) * 32;
  unsigned int* pbas = ctrs + ((dir * 2 + nt) * 4) * 32;

  // zero-init own h0 cells (2 u64 = 8 rows x 1 batch)
  {
    u64* pza = (u64*)(hbuf + ((long)(0 * 2 + dir) * B_ + b_idx) * H_ + r0a);
    u64* pzb = (u64*)(hbuf + ((long)(0 * 2 + dir) * B_ + b_idx) * H_ + r0b);
    __hip_atomic_store(pza, (u64)0, __ATOMIC_RELAXED, __HIP_MEMORY_SCOPE_AGENT);
    __hip_atomic_store(pzb, (u64)0, __ATOMIC_RELAXED, __HIP_MEMORY_SCOPE_AGENT);
  }
  asm volatile("s_waitcnt vmcnt(0)" ::: "memory");
  __syncthreads();  // W LDS visible to all waves
  if (lane == 0)
    __hip_atomic_fetch_add(sig, 1u, __ATOMIC_RELAXED, __HIP_MEMORY_SCOPE_AGENT);

  // 1-step-ahead xp prefetch (own cells only)
  const int s0 = dir ? (S_ - 1) : 0;
  long oa_n = ((long)b_idx * S_ + s0) * (2 * H_) + dir * H_ + r0a;
  long ob_n = ((long)b_idx * S_ + s0) * (2 * H_) + dir * H_ + r0b;
  floatx4 xpa_n = *(const floatx4*)(out + oa_n);
  floatx4 xpb_n = *(const floatx4*)(out + ob_n);

#pragma unroll 1
  for (int t = 0; t < S_; ++t) {
    const int p = t & 1;

    // ---- autonomous poll: 4 sub-counters of my (dir,nt) block ----
    {
      const unsigned int tgt = 8u * (unsigned)(t + 1);
      for (;;) {
        unsigned int v = tgt;
        if (lane < 4)
          v = __hip_atomic_load(pbas + lane * 32, __ATOMIC_RELAXED, __HIP_MEMORY_SCOPE_AGENT);
        if (__all((int)(v >= tgt))) break;
        __builtin_amdgcn_s_sleep(1);
      }
    }

    // ---- batched h loads: 16 x dwordx4 sc1, one exposed MALL latency ----
    const _Float16* hp = hbuf + ((long)(p * 2 + dir) * B_ + b_idx) * H_ + kbase + lkg * 8;
    half8 hr[16];
#pragma unroll
    for (int kt = 0; kt < 16; ++kt)
      asm volatile("global_load_dwordx4 %0, %1, off offset:%2 sc1"
                   : "=v"(hr[kt]) : "v"(hp), "i"(kt * 64) : "memory");
    asm volatile("s_waitcnt vmcnt(0)" ::: "memory");
    __builtin_amdgcn_sched_barrier(0);

    // ---- MFMA: 4 row tiles x this K-half ----
    floatx4 a0 = {}, a1 = {}, a2 = {}, a3 = {};
#pragma unroll
    for (int kt = 0; kt < 16; ++kt) {
      const int koff = kt * 64 + lkg * 16;
      half8 w0 = *(const half8*)((const char*)wlds + ((abase0 + koff) ^ asw));
      half8 w1 = *(const half8*)((const char*)wlds + ((abase1 + koff) ^ asw));
      half8 w2 = *(const half8*)((const char*)wlds + ((abase2 + koff) ^ asw));
      half8 w3 = *(const half8*)((const char*)wlds + ((abase3 + koff) ^ asw));
      a0 = __builtin_amdgcn_mfma_f32_16x16x32_f16(w0, hr[kt], a0, 0, 0, 0);
      a1 = __builtin_amdgcn_mfma_f32_16x16x32_f16(w1, hr[kt], a1, 0, 0, 0);
      a2 = __builtin_amdgcn_mfma_f32_16x16x32_f16(w2, hr[kt], a2, 0, 0, 0);
      a3 = __builtin_amdgcn_mfma_f32_16x16x32_f16(w3, hr[kt], a3, 0, 0, 0);
    }

    // ---- kh partial exchange: ship the 2 non-owned tiles ----
    {
      const int shipA = (1 - kh) * 2;      // tiles shipped: shipA, shipA+1
      floatx4 sA = kh ? a0 : a2;
      floatx4 sB = kh ? a1 : a3;
      redlds[((p * 4 + shipA    ) * 2 + nt) * 64 + lane] = sA;
      redlds[((p * 4 + shipA + 1) * 2 + nt) * 64 + lane] = sB;
    }
    __syncthreads();
    const int ownA = kh * 2;
    floatx4 totA = (kh ? a2 : a0) + redlds[((p * 4 + ownA    ) * 2 + nt) * 64 + lane];
    floatx4 totB = (kh ? a3 : a1) + redlds[((p * 4 + ownA + 1) * 2 + nt) * 64 + lane];

    const long oa = oa_n, ob = ob_n;
    const floatx4 xpa = xpa_n, xpb = xpb_n;
    floatx4 hva, hvb;
#pragma unroll
    for (int v = 0; v < 4; ++v) {
      float za = totA[v] + xpa[v];
      float zb = totB[v] + xpb[v];
      hva[v] = 1.f - 2.f / (__expf(2.f * za) + 1.f);   // tanh
      hvb[v] = 1.f - 2.f / (__expf(2.f * zb) + 1.f);
    }

    if (t + 1 < S_) {
      // h stores (sc1) -> own-wave ack -> per-wave signal
      union { half4v h; u64 u; } ha, hb;
      ha.h = half4v{(_Float16)hva[0], (_Float16)hva[1], (_Float16)hva[2], (_Float16)hva[3]};
      hb.h = half4v{(_Float16)hvb[0], (_Float16)hvb[1], (_Float16)hvb[2], (_Float16)hvb[3]};
      u64* da = (u64*)(hbuf + ((long)((1 - p) * 2 + dir) * B_ + b_idx) * H_ + r0a);
      u64* db = (u64*)(hbuf + ((long)((1 - p) * 2 + dir) * B_ + b_idx) * H_ + r0b);
      __hip_atomic_store(da, ha.u, __ATOMIC_RELAXED, __HIP_MEMORY_SCOPE_AGENT);
      __hip_atomic_store(db, hb.u, __ATOMIC_RELAXED, __HIP_MEMORY_SCOPE_AGENT);
      asm volatile("s_waitcnt vmcnt(0)" ::: "memory");
      if (lane == 0)
        __hip_atomic_fetch_add(sig, 1u, __ATOMIC_RELAXED, __HIP_MEMORY_SCOPE_AGENT);
    }

    // out stores + next xp prefetch AFTER the signal (acks overlap next poll)
    *(floatx4*)(out + oa) = hva;
    *(floatx4*)(out + ob) = hvb;
    if (t + 1 < S_) {
      const int sidx1 = dir ? (S_ - 2 - t) : (t + 1);
      oa_n = ((long)b_idx * S_ + sidx1) * (2 * H_) + dir * H_ + r0a;
      ob_n = ((long)b_idx * S_ + sidx1) * (2 * H_) + dir * H_ + r0b;
      xpa_n = *(const floatx4*)(out + oa_n);
      xpb_n = *(const floatx4*)(out + ob_n);
    }
  }
}

// ---------------------------------------------------------------------------
extern "C" void kernel_launch(void* const* d_in, const int* in_sizes, int n_in,
                              void* d_out, int out_size, void* d_ws, size_t ws_size,
                              hipStream_t stream) {
  const float* x    = (const float*)d_in[0];
  const float* Wihf = (const float*)d_in[1];
  const float* Whhf = (const float*)d_in[2];
  const float* bihf = (const float*)d_in[3];
  const float* bhhf = (const float*)d_in[4];
  const float* Wihb = (const float*)d_in[5];
  const float* Whhb = (const float*)d_in[6];
  const float* bihb = (const float*)d_in[7];
  const float* bhhb = (const float*)d_in[8];
  float* out = (float*)d_out;

  // workspace layout
  char* ws = (char*)d_ws;
  _Float16*     x16  = (_Float16*)ws;                          // 32 MiB
  _Float16*     w16  = (_Float16*)(ws + 33554432u);            // 4 MiB
  float*        bias = (float*)   (ws + 33554432u + 4194304u); // 8 KiB
  _Float16*     hbuf = (_Float16*)(ws + 37756928u);            // 256 KiB
  unsigned int* ctrs = (unsigned int*)(ws + 38019072u);        // 4 KiB

  cvt_f32_f16<<<4096, 256, 0, stream>>>(x, x16, (long)M_TOT * I_);
  cvt_f32_f16<<<1024, 256, 0, stream>>>(Wihf, w16, (long)H_ * I_);
  cvt_f32_f16<<<1024, 256, 0, stream>>>(Wihb, w16 + (long)H_ * I_, (long)H_ * I_);
  bias_sum_kernel<<<4, 256, 0, stream>>>(bihf, bhhf, bihb, bhhb, bias, ctrs);

  dim3 g(H_ / 128, M_TOT / 128, 2);
  gemm_xp_kernel<<<g, 256, 0, stream>>>(x16, w16, bias, out);

  void* args[] = {(void*)&Whhf, (void*)&Whhb, (void*)&out, (void*)&hbuf, (void*)&ctrs};
  (void)hipLaunchCooperativeKernel((void*)scan_kernel, dim3(32), dim3(256),
                                   args, 0, stream);
}

// Round 11
// 2211.060 us; speedup vs baseline: 1.2730x; 1.2730x over previous
//
#include <hip/hip_runtime.h>

typedef _Float16 half8  __attribute__((ext_vector_type(8)));
typedef _Float16 half4v __attribute__((ext_vector_type(4)));
typedef float    floatx4 __attribute__((ext_vector_type(4)));
typedef unsigned long long u64;

#define B_ 32
#define S_ 512
#define I_ 1024
#define H_ 1024
#define M_TOT (B_ * S_)   // 16384

// ---------------------------------------------------------------------------
// fp32 -> fp16 conversion (vectorized, grid-stride), n multiple of 4
// ---------------------------------------------------------------------------
__global__ void cvt_f32_f16(const float* __restrict__ src, _Float16* __restrict__ dst, long n) {
  long i = ((long)blockIdx.x * blockDim.x + threadIdx.x) * 4;
  const long stride = (long)gridDim.x * blockDim.x * 4;
  for (; i < n; i += stride) {
    floatx4 v = *(const floatx4*)(src + i);
    half4v h = {(_Float16)v[0], (_Float16)v[1], (_Float16)v[2], (_Float16)v[3]};
    *(half4v*)(dst + i) = h;
  }
}

__global__ void bias_sum_kernel(const float* __restrict__ bihf, const float* __restrict__ bhhf,
                                const float* __restrict__ bihb, const float* __restrict__ bhhb,
                                float* __restrict__ bias) {
  int i = blockIdx.x * blockDim.x + threadIdx.x;
  if (i < H_) {
    bias[i]      = bihf[i] + bhhf[i];
    bias[H_ + i] = bihb[i] + bhhb[i];
  }
}

// ---------------------------------------------------------------------------
// Ring init (every launch -> graph-replay deterministic).
// slot0 = h[0] zeros (halves 0x0000, LSB 0 == tag of h[0]);
// slot1 = 0x0002 halves (LSB 0 != expected tag 1 -> consumers spin);
// slot2 = 0x0001 halves (LSB 1 != expected tag 0 -> consumers spin).
// 3 slots x 2 dir x 32 b x 1024 halves = 98304 u32.
// ---------------------------------------------------------------------------
__global__ void init_ring(unsigned int* __restrict__ hq) {
  const int i = blockIdx.x * blockDim.x + threadIdx.x;
  unsigned int v = 0u;
  if (i >= 32768) v = (i < 65536) ? 0x00020002u : 0x00010001u;
  __hip_atomic_store(hq + i, v, __ATOMIC_RELAXED, __HIP_MEMORY_SCOPE_AGENT);
}

// ---------------------------------------------------------------------------
// GEMM: xp[dir][m][n] = sum_k x16[m][k] * W16[dir][n][k] + bias[dir][n]
// stored into out[m*2048 + dir*1024 + n] (xp lives in d_out; scan updates it
// in place).
// ---------------------------------------------------------------------------
__global__ void __launch_bounds__(256) gemm_xp_kernel(
    const _Float16* __restrict__ A,
    const _Float16* __restrict__ W,
    const float*    __restrict__ bias,
    float*          __restrict__ out)
{
  __shared__ _Float16 alds[128 * 32];
  __shared__ _Float16 blds[128 * 32];

  const int dir = blockIdx.z;
  const int m0  = blockIdx.y * 128;
  const int n0  = blockIdx.x * 128;
  const int tid  = threadIdx.x;
  const int lane = tid & 63;
  const int wv   = tid >> 6;
  const int wm   = wv >> 1, wn = wv & 1;
  const int lrow = lane & 15;
  const int lkg  = lane >> 4;

  const _Float16* Wd = W + (long)dir * H_ * I_;

  floatx4 acc[4][4] = {};

  const int srow = tid >> 1;
  const int sseg = tid & 1;

  for (int kt = 0; kt < 32; ++kt) {
    __syncthreads();
    {
      const _Float16* srcA = A  + (long)(m0 + srow) * I_ + kt * 32 + sseg * 16;
      const _Float16* srcB = Wd + (long)(n0 + srow) * I_ + kt * 32 + sseg * 16;
      half8 a0 = *(const half8*)(srcA);
      half8 a1 = *(const half8*)(srcA + 8);
      half8 b0 = *(const half8*)(srcB);
      half8 b1 = *(const half8*)(srcB + 8);
      const int sw = (srow & 7) << 4;
      const int base = srow * 64 + sseg * 32;
      *(half8*)((char*)alds + ((base     ) ^ sw)) = a0;
      *(half8*)((char*)alds + ((base + 16) ^ sw)) = a1;
      *(half8*)((char*)blds + ((base     ) ^ sw)) = b0;
      *(half8*)((char*)blds + ((base + 16) ^ sw)) = b1;
    }
    __syncthreads();

    half8 af[4], bf[4];
#pragma unroll
    for (int mt = 0; mt < 4; ++mt) {
      int r = wm * 64 + mt * 16 + lrow;
      int byte = (r * 64 + lkg * 16) ^ ((r & 7) << 4);
      af[mt] = *(const half8*)((const char*)alds + byte);
    }
#pragma unroll
    for (int ntt = 0; ntt < 4; ++ntt) {
      int r = wn * 64 + ntt * 16 + lrow;
      int byte = (r * 64 + lkg * 16) ^ ((r & 7) << 4);
      bf[ntt] = *(const half8*)((const char*)blds + byte);
    }
#pragma unroll
    for (int mt = 0; mt < 4; ++mt)
#pragma unroll
      for (int ntt = 0; ntt < 4; ++ntt)
        acc[mt][ntt] = __builtin_amdgcn_mfma_f32_16x16x32_f16(af[mt], bf[ntt], acc[mt][ntt], 0, 0, 0);
  }

#pragma unroll
  for (int mt = 0; mt < 4; ++mt) {
    int mrow = m0 + wm * 64 + mt * 16 + lkg * 4;
#pragma unroll
    for (int ntt = 0; ntt < 4; ++ntt) {
      int n = n0 + wn * 64 + ntt * 16 + lrow;
      float bv = bias[dir * H_ + n];
#pragma unroll
      for (int v = 0; v < 4; ++v) {
        out[(long)(mrow + v) * (2 * H_) + dir * H_ + n] = acc[mt][ntt][v] + bv;
      }
    }
  }
}

// ---------------------------------------------------------------------------
// Recurrent scan, data-embedded-epoch edition (R9 geometry, sync REMOVED).
// 64 WGs: dir = wg>>5, rb = wg&31 owns rows [rb*32,+32). Waves (nt, kh).
// h ring: hbuf[3][2 dir][B][H] f16; h[j] lives in slot j%3, and EVERY stored
// f16 half has its mantissa LSB forced to j&1 (tanh in [-1,1]: <=1 ulp cost).
// Consumer at iter t speculatively loads slot t%3 and checks all halves'
// LSB == t&1 -- freshness and data arrive in the SAME load; stale slot
// content is h[t-3] with LSB (t-3)&1 != t&1. No counters, no producer
// vmcnt-ack, no flag stores, no prologue barrier.
// Ring-3 overwrite safety (no clearance): wave at iter t+1 saw fresh h[t+1]
// => its 32 producers read fresh h[t] => THEIR producers (= all 64 (dir,nt)
// waves) completed iter t-1 => all reads of h[t-1] (what slot (t+2)%3 holds)
// are done. Data dependency bounds skew <= 1.
// Replay-determinism: init_ring rewrites all 3 slots before every scan.
// ---------------------------------------------------------------------------
__global__ void __launch_bounds__(256, 1) scan_kernel(
    const float* __restrict__ Whh_f,
    const float* __restrict__ Whh_b,
    float*       __restrict__ out,     // [B][S][2H]; holds xp on entry
    _Float16*    __restrict__ hbuf)    // [3 slot][2 dir][B][H] f16
{
  __shared__ _Float16 wlds[32 * 1024];     // 64 KiB
  __shared__ floatx4  redlds[2 * 4 * 64];  // 8 KiB, parity-double-buffered

  const int w     = blockIdx.x;
  const int dir   = w >> 5;
  const int rb    = w & 31;
  const int rows0 = rb * 32;
  const float* Whh = dir ? Whh_b : Whh_f;
  const int tid = threadIdx.x;

  // stage W_hh rows [rows0, rows0+32) as f16, swizzled: byte ^= (row&7)<<4
  for (int idx = tid; idx < 32 * 128; idx += 256) {
    const int r  = idx >> 7;
    const int kg = idx & 127;
    const float* src = Whh + (long)(rows0 + r) * H_ + kg * 8;
    floatx4 v0 = *(const floatx4*)(src);
    floatx4 v1 = *(const floatx4*)(src + 4);
    half8 h = {(_Float16)v0[0], (_Float16)v0[1], (_Float16)v0[2], (_Float16)v0[3],
               (_Float16)v1[0], (_Float16)v1[1], (_Float16)v1[2], (_Float16)v1[3]};
    const int byte = (r * 2048 + kg * 16) ^ ((r & 7) << 4);
    *(half8*)((char*)wlds + byte) = h;
  }

  // wave/lane roles (R9)
  const int lane = tid & 63;
  const int wv   = tid >> 6;
  const int nt   = wv & 1;          // batch half
  const int kh   = wv >> 1;         // K half / owned row tile
  const int lrow = lane & 15;
  const int lkg  = lane >> 4;       // 0..3
  const int b_idx = nt * 16 + lrow; // batch
  const int kbase = kh * 512;       // K-half start (halves)
  const int r0    = rows0 + kh * 16 + lkg * 4;  // this lane's 4 output rows
  const int asw   = (lrow & 7) << 4;
  const int abase0 = lrow * 2048 + kbase * 2;        // tile0 row byte base
  const int abase1 = (16 + lrow) * 2048 + kbase * 2; // tile1 row byte base

  const long hstride = (long)2 * B_ * H_;  // slot stride in halves

  __syncthreads();  // W LDS visible to all waves

  // 1-step-ahead xp prefetch (own cells only)
  long o_nxt = ((long)b_idx * S_ + (dir ? (S_ - 1) : 0)) * (2 * H_) + dir * H_ + r0;
  floatx4 xp_n = *(const floatx4*)(out + o_nxt);

  int s_in = 0;  // slot of h[t]

#pragma unroll 1
  for (int t = 0; t < S_; ++t) {
    const int p = t & 1;
    const int s_out = (s_in == 2) ? 0 : (s_in + 1);

    // ---- speculative tag-checked h loads: freshness == data ----
    const _Float16* hp = hbuf + (s_in * hstride) + ((long)dir * B_ + b_idx) * H_ + kbase + lkg * 8;
    const unsigned int rep = (unsigned)(t & 1) * 0x00010001u;  // expected LSB pattern
    half8 hr[16];
    for (;;) {
#pragma unroll
      for (int kt = 0; kt < 16; ++kt)
        asm volatile("global_load_dwordx4 %0, %1, off offset:%2 sc1"
                     : "=v"(hr[kt]) : "v"(hp), "i"(kt * 64) : "memory");
      asm volatile("s_waitcnt vmcnt(0)" ::: "memory");
      unsigned int bad = 0;
#pragma unroll
      for (int kt = 0; kt < 16; ++kt) {
        union { half8 h; unsigned int u[4]; } c; c.h = hr[kt];
        bad |= ((c.u[0] ^ rep) | (c.u[1] ^ rep) | (c.u[2] ^ rep) | (c.u[3] ^ rep))
               & 0x00010001u;
      }
      if (!__any(bad != 0)) break;
    }
    __builtin_amdgcn_sched_barrier(0);

    // ---- MFMA: both row tiles, this K-half ----
    floatx4 a0 = {}, a1 = {};
#pragma unroll
    for (int kt = 0; kt < 16; ++kt) {
      const int koff = kt * 64 + lkg * 16;
      half8 wa = *(const half8*)((const char*)wlds + ((abase0 + koff) ^ asw));
      half8 wb = *(const half8*)((const char*)wlds + ((abase1 + koff) ^ asw));
      a0 = __builtin_amdgcn_mfma_f32_16x16x32_f16(wa, hr[kt], a0, 0, 0, 0);
      a1 = __builtin_amdgcn_mfma_f32_16x16x32_f16(wb, hr[kt], a1, 0, 0, 0);
    }

    // ---- kh partial exchange (parity-buffered), ONE syncthreads/step ----
    redlds[((p * 2 + (1 - kh)) * 2 + nt) * 64 + lane] = kh ? a0 : a1;
    __syncthreads();
    floatx4 tot = (kh ? a1 : a0) + redlds[((p * 2 + kh) * 2 + nt) * 64 + lane];

    const long o = o_nxt;
    const floatx4 xpv = xp_n;
    floatx4 hv;
#pragma unroll
    for (int v = 0; v < 4; ++v) {
      float z = tot[v] + xpv[v];
      hv[v] = 1.f - 2.f / (__expf(2.f * z) + 1.f);   // tanh(z)
    }

    if (t + 1 < S_) {
      // pack h[t+1], force every half's LSB to (t+1)&1, single u64 store.
      // NO vmcnt ack, NO signal -- the data IS the signal.
      union { half4v h; u64 u; unsigned int w2[2]; } hh;
      hh.h = half4v{(_Float16)hv[0], (_Float16)hv[1], (_Float16)hv[2], (_Float16)hv[3]};
      const unsigned int eo = (unsigned)((t + 1) & 1) * 0x00010001u;
      hh.w2[0] = (hh.w2[0] & ~0x00010001u) | eo;
      hh.w2[1] = (hh.w2[1] & ~0x00010001u) | eo;
      u64* dst = (u64*)(hbuf + (s_out * hstride) + ((long)dir * B_ + b_idx) * H_ + r0);
      __hip_atomic_store(dst, hh.u, __ATOMIC_RELAXED, __HIP_MEMORY_SCOPE_AGENT);
    }

    // out store + next xp prefetch (drain in background)
    *(floatx4*)(out + o) = hv;
    if (t + 1 < S_) {
      const int sidx1 = dir ? (S_ - 2 - t) : (t + 1);
      o_nxt = ((long)b_idx * S_ + sidx1) * (2 * H_) + dir * H_ + r0;
      xp_n = *(const floatx4*)(out + o_nxt);
    }
    s_in = s_out;
  }
}

// ---------------------------------------------------------------------------
extern "C" void kernel_launch(void* const* d_in, const int* in_sizes, int n_in,
                              void* d_out, int out_size, void* d_ws, size_t ws_size,
                              hipStream_t stream) {
  const float* x    = (const float*)d_in[0];
  const float* Wihf = (const float*)d_in[1];
  const float* Whhf = (const float*)d_in[2];
  const float* bihf = (const float*)d_in[3];
  const float* bhhf = (const float*)d_in[4];
  const float* Wihb = (const float*)d_in[5];
  const float* Whhb = (const float*)d_in[6];
  const float* bihb = (const float*)d_in[7];
  const float* bhhb = (const float*)d_in[8];
  float* out = (float*)d_out;

  // workspace layout
  char* ws = (char*)d_ws;
  _Float16*     x16  = (_Float16*)ws;                          // 32 MiB
  _Float16*     w16  = (_Float16*)(ws + 33554432u);            // 4 MiB
  float*        bias = (float*)   (ws + 33554432u + 4194304u); // 8 KiB
  _Float16*     hbuf = (_Float16*)(ws + 37756928u);            // 384 KiB ring

  cvt_f32_f16<<<4096, 256, 0, stream>>>(x, x16, (long)M_TOT * I_);
  cvt_f32_f16<<<1024, 256, 0, stream>>>(Wihf, w16, (long)H_ * I_);
  cvt_f32_f16<<<1024, 256, 0, stream>>>(Wihb, w16 + (long)H_ * I_, (long)H_ * I_);
  bias_sum_kernel<<<4, 256, 0, stream>>>(bihf, bhhf, bihb, bhhb, bias);
  init_ring<<<384, 256, 0, stream>>>((unsigned int*)hbuf);

  dim3 g(H_ / 128, M_TOT / 128, 2);
  gemm_xp_kernel<<<g, 256, 0, stream>>>(x16, w16, bias, out);

  void* args[] = {(void*)&Whhf, (void*)&Whhb, (void*)&out, (void*)&hbuf};
  (void)hipLaunchCooperativeKernel((void*)scan_kernel, dim3(64), dim3(256),
                                   args, 0, stream);
}